// Round 4
// baseline (1060.928 us; speedup 1.0000x reference)
//
#include <hip/hip_runtime.h>
#include <math.h>

#define NN 100000
#define NE 1600000
#define NPAIR (NN / 2)
#define D 64
#define DM 32
#define PAD 68            // padded row stride (floats) for transposed weights in LDS
#define SCAN_CHUNK 1024
#define NBLK_SCAN ((NN + SCAN_CHUNK - 1) / SCAN_CHUNK)   // 98

__device__ __forceinline__ float bcastf(float v, int k) {
    return __uint_as_float(__builtin_amdgcn_readlane(__float_as_uint(v), k));
}

// ---------- CSR build ----------
__global__ __launch_bounds__(256) void hist_kernel(
    const int* __restrict__ dst, int* __restrict__ hist, int nEdges)
{
    for (int e = blockIdx.x * 256 + threadIdx.x; e < nEdges; e += gridDim.x * 256)
        atomicAdd(&hist[dst[e]], 1);
}

__global__ __launch_bounds__(256) void block_sum_kernel(
    const int* __restrict__ hist, int* __restrict__ partials, int n)
{
    __shared__ int red[256];
    int t = threadIdx.x;
    int base = blockIdx.x * SCAN_CHUNK + t * 4;
    int tot = 0;
#pragma unroll
    for (int k = 0; k < 4; ++k)
        if (base + k < n) tot += hist[base + k];
    red[t] = tot;
    __syncthreads();
    for (int off = 128; off >= 1; off >>= 1) {
        if (t < off) red[t] += red[t + off];
        __syncthreads();
    }
    if (t == 0) partials[blockIdx.x] = red[0];
}

__global__ __launch_bounds__(128) void scan_partials_kernel(
    const int* __restrict__ partials, int* __restrict__ pscan, int nb)
{
    __shared__ int l[128];
    int t = threadIdx.x;
    if (t < nb) l[t] = partials[t];
    __syncthreads();
    if (t == 0) {
        int run = 0;
        for (int i = 0; i < nb; ++i) { int tmp = l[i]; l[i] = run; run += tmp; }
    }
    __syncthreads();
    if (t < nb) pscan[t] = l[t];
}

__global__ __launch_bounds__(256) void scan_chunk_kernel(
    const int* __restrict__ hist, const int* __restrict__ pscan,
    int* __restrict__ rowBeg, int* __restrict__ cursor, int n)
{
    __shared__ int lsum[256];
    int t = threadIdx.x;
    int base = blockIdx.x * SCAN_CHUNK + t * 4;
    int v[4];
    int tot = 0;
#pragma unroll
    for (int k = 0; k < 4; ++k) {
        v[k] = (base + k < n) ? hist[base + k] : 0;
        tot += v[k];
    }
    lsum[t] = tot;
    __syncthreads();
    for (int off = 1; off < 256; off <<= 1) {
        int x = (t >= off) ? lsum[t - off] : 0;
        __syncthreads();
        lsum[t] += x;
        __syncthreads();
    }
    int run = pscan[blockIdx.x] + lsum[t] - tot;
#pragma unroll
    for (int k = 0; k < 4; ++k) {
        if (base + k < n) {
            rowBeg[base + k] = run;
            cursor[base + k] = run;
            run += v[k];
        }
    }
}

__global__ __launch_bounds__(256) void fill_kernel(
    const int* __restrict__ src, const int* __restrict__ dst,
    int* __restrict__ cursor, int* __restrict__ sortedSrc, int nEdges)
{
    for (int e = blockIdx.x * 256 + threadIdx.x; e < nEdges; e += gridDim.x * 256) {
        int pos = atomicAdd(&cursor[dst[e]], 1);
        sortedSrc[pos] = src[e];
    }
}

// ---------- float4 gather: sum of h[src] rows over one node's segment ----------
// Lane layout: group g = lane>>4 (4 groups), slot q = lane&15.
// One dwordx4 load fetches 4 neighbor rows (one per group); per-group partial
// sums are combined by the caller via shfl_xor(16|32).
__device__ __forceinline__ float4 gather4(
    const float4* __restrict__ h4, const int* __restrict__ sortedSrc,
    int beg, int deg, int lane, int g, int q, int g4)
{
    float4 acc = make_float4(0.f, 0.f, 0.f, 0.f);
    for (int c = 0; c < deg; c += 64) {
        int cl = min(64, deg - c);
        int idx = (lane < cl) ? sortedSrc[beg + c + lane] : 0;
        int nq = cl >> 2;
        int addr = g4;                      // bpermute byte addr = 16*i + 4*g
        for (int i = 0; i < nq; ++i) {
            int s = __builtin_amdgcn_ds_bpermute(addr, idx);
            float4 v = h4[(size_t)s * 16 + q];
            acc.x += v.x; acc.y += v.y; acc.z += v.z; acc.w += v.w;
            addr += 16;
        }
        int rem = cl & 3;
        if (rem) {
            int s = __builtin_amdgcn_ds_bpermute(addr, idx);
            if (g < rem) {
                float4 v = h4[(size_t)s * 16 + q];
                acc.x += v.x; acc.y += v.y; acc.z += v.z; acc.w += v.w;
            }
        }
    }
    return acc;
}

__device__ __forceinline__ void xor_reduce4(float4& a)
{
#pragma unroll
    for (int off = 16; off <= 32; off <<= 1) {
        a.x += __shfl_xor(a.x, off);
        a.y += __shfl_xor(a.y, off);
        a.z += __shfl_xor(a.z, off);
        a.w += __shfl_xor(a.w, off);
    }
}

// GEMV accumulate for one node: acc += m@Wl + xr@Wr restricted to k0..k0+3.
// m/xr live as float4 (feature 4q+c at slot-lane q); q0 = k0>>2 compile-time.
#define GEMV4(accv, mv, xv, wl, wr, q0)                                   \
    accv += bcastf((mv).x, q0) * (wl).x + bcastf((xv).x, q0) * (wr).x     \
          + bcastf((mv).y, q0) * (wl).y + bcastf((xv).y, q0) * (wr).y     \
          + bcastf((mv).z, q0) * (wl).z + bcastf((xv).z, q0) * (wr).z     \
          + bcastf((mv).w, q0) * (wl).w + bcastf((xv).w, q0) * (wr).w;

// ---------- fused layer 1: gather-mean + GEMV + relu (2 nodes per wave) ----------
__global__ __launch_bounds__(512, 4) void sage_layer1_kernel(
    const float* __restrict__ hin,
    const int* __restrict__ rowBeg, const int* __restrict__ deg,
    const int* __restrict__ sortedSrc,
    const float* __restrict__ Wl, const float* __restrict__ bl,
    const float* __restrict__ Wr,
    float* __restrict__ hout, int nPair)
{
    __shared__ float sWlT[D * PAD];
    __shared__ float sWrT[D * PAD];
    __shared__ float sBl[D];
    for (int i = threadIdx.x; i < D * D; i += 512) {
        int k = i >> 6, j = i & 63;        // global layout W[k][j]
        sWlT[j * PAD + k] = Wl[i];
        sWrT[j * PAD + k] = Wr[i];
    }
    if (threadIdx.x < D) sBl[threadIdx.x] = bl[threadIdx.x];
    __syncthreads();

    int lane = threadIdx.x & 63;
    int wid = threadIdx.x >> 6;            // 8 waves/block
    int g = lane >> 4, q = lane & 15, g4 = g << 2;
    const float4* hin4 = (const float4*)hin;
    const float* rowWl = &sWlT[lane * PAD];
    const float* rowWr = &sWrT[lane * PAD];

    for (int p = blockIdx.x * 8 + wid; p < nPair; p += gridDim.x * 8) {
        int nA = p * 2, nB = p * 2 + 1;
        int dgA = deg[nA], dgB = deg[nB];

        float4 mA = gather4(hin4, sortedSrc, rowBeg[nA], dgA, lane, g, q, g4);
        float4 mB = gather4(hin4, sortedSrc, rowBeg[nB], dgB, lane, g, q, g4);
        xor_reduce4(mA);
        xor_reduce4(mB);
        float invA = (dgA > 0) ? (1.0f / (float)dgA) : 0.0f;
        float invB = (dgB > 0) ? (1.0f / (float)dgB) : 0.0f;
        mA.x *= invA; mA.y *= invA; mA.z *= invA; mA.w *= invA;
        mB.x *= invB; mB.y *= invB; mB.z *= invB; mB.w *= invB;

        float4 xA = hin4[(size_t)nA * 16 + q];
        float4 xB = hin4[(size_t)nB * 16 + q];

        float accA = sBl[lane], accB = sBl[lane];
#pragma unroll
        for (int k0 = 0; k0 < D; k0 += 4) {
            const int q0 = k0 >> 2;
            float4 wl = *(const float4*)&rowWl[k0];
            float4 wr = *(const float4*)&rowWr[k0];
            GEMV4(accA, mA, xA, wl, wr, q0);
            GEMV4(accB, mB, xB, wl, wr, q0);
        }
        hout[(size_t)nA * D + lane] = fmaxf(accA, 0.0f);
        hout[(size_t)nB * D + lane] = fmaxf(accB, 0.0f);
    }
}

// ---------- fused layer 2 + MLP head (2 nodes per wave) ----------
__global__ __launch_bounds__(512, 4) void sage_layer2_mlp_kernel(
    const float* __restrict__ hin,
    const int* __restrict__ rowBeg, const int* __restrict__ deg,
    const int* __restrict__ sortedSrc,
    const float* __restrict__ W2l, const float* __restrict__ b2l,
    const float* __restrict__ W2r,
    const float* __restrict__ Wf1, const float* __restrict__ bf1,
    const float* __restrict__ Wf2, const float* __restrict__ bf2,
    float* __restrict__ out, int nPair)
{
    __shared__ float sWlT[D * PAD];
    __shared__ float sWrT[D * PAD];
    __shared__ float sF1T[DM * PAD];
    __shared__ float sBl[D];
    __shared__ float sBf1[DM];
    __shared__ float sF2[DM];
    __shared__ float sBf2;
    for (int i = threadIdx.x; i < D * D; i += 512) {
        int k = i >> 6, j = i & 63;
        sWlT[j * PAD + k] = W2l[i];
        sWrT[j * PAD + k] = W2r[i];
    }
    for (int i = threadIdx.x; i < D * DM; i += 512) {
        int k = i >> 5, j = i & 31;        // Wf1[k][j]
        sF1T[j * PAD + k] = Wf1[i];
    }
    if (threadIdx.x < D) sBl[threadIdx.x] = b2l[threadIdx.x];
    if (threadIdx.x < DM) {
        sBf1[threadIdx.x] = bf1[threadIdx.x];
        sF2[threadIdx.x] = Wf2[threadIdx.x];
    }
    if (threadIdx.x == 0) sBf2 = bf2[0];
    __syncthreads();

    int lane = threadIdx.x & 63;
    int wid = threadIdx.x >> 6;
    int g = lane >> 4, q = lane & 15, g4 = g << 2;
    bool loHalf = (lane < 32);
    const float4* hin4 = (const float4*)hin;
    const float* rowWl = &sWlT[lane * PAD];
    const float* rowWr = &sWrT[lane * PAD];
    const float* rowF1 = &sF1T[(lane & 31) * PAD];

    for (int p = blockIdx.x * 8 + wid; p < nPair; p += gridDim.x * 8) {
        int nA = p * 2, nB = p * 2 + 1;
        int dgA = deg[nA], dgB = deg[nB];

        float4 mA = gather4(hin4, sortedSrc, rowBeg[nA], dgA, lane, g, q, g4);
        float4 mB = gather4(hin4, sortedSrc, rowBeg[nB], dgB, lane, g, q, g4);
        xor_reduce4(mA);
        xor_reduce4(mB);
        float invA = (dgA > 0) ? (1.0f / (float)dgA) : 0.0f;
        float invB = (dgB > 0) ? (1.0f / (float)dgB) : 0.0f;
        mA.x *= invA; mA.y *= invA; mA.z *= invA; mA.w *= invA;
        mB.x *= invB; mB.y *= invB; mB.z *= invB; mB.w *= invB;

        float4 xA = hin4[(size_t)nA * 16 + q];
        float4 xB = hin4[(size_t)nB * 16 + q];

        float accA = sBl[lane], accB = sBl[lane];
#pragma unroll
        for (int k0 = 0; k0 < D; k0 += 4) {
            const int q0 = k0 >> 2;
            float4 wl = *(const float4*)&rowWl[k0];
            float4 wr = *(const float4*)&rowWr[k0];
            GEMV4(accA, mA, xA, wl, wr, q0);
            GEMV4(accB, mB, xB, wl, wr, q0);
        }
        float h2A = fmaxf(accA, 0.0f);
        float h2B = fmaxf(accB, 0.0f);

        // MLP layer 1: lanes 0-31 compute node A's 32 features, lanes 32-63 node B's.
        float acc2 = sBf1[lane & 31];
#pragma unroll
        for (int k0 = 0; k0 < D; k0 += 4) {
            float4 f1 = *(const float4*)&rowF1[k0];
            float a0 = loHalf ? bcastf(h2A, k0 + 0) : bcastf(h2B, k0 + 0);
            float a1 = loHalf ? bcastf(h2A, k0 + 1) : bcastf(h2B, k0 + 1);
            float a2 = loHalf ? bcastf(h2A, k0 + 2) : bcastf(h2B, k0 + 2);
            float a3 = loHalf ? bcastf(h2A, k0 + 3) : bcastf(h2B, k0 + 3);
            acc2 += a0 * f1.x + a1 * f1.y + a2 * f1.z + a3 * f1.w;
        }
        float pv = fmaxf(acc2, 0.0f) * sF2[lane & 31];
#pragma unroll
        for (int off = 16; off >= 1; off >>= 1) pv += __shfl_xor(pv, off);

        if (lane == 0) {
            float z = pv + sBf2;
            out[nA] = 1.0f / (1.0f + expf(-z));
        }
        if (lane == 32) {
            float z = pv + sBf2;
            out[nB] = 1.0f / (1.0f + expf(-z));
        }
    }
}

extern "C" void kernel_launch(void* const* d_in, const int* in_sizes, int n_in,
                              void* d_out, int out_size, void* d_ws, size_t ws_size,
                              hipStream_t stream)
{
    const float* x   = (const float*)d_in[0];
    const int*   ei  = (const int*)d_in[1];
    const float* W1l = (const float*)d_in[2];
    const float* b1l = (const float*)d_in[3];
    const float* W1r = (const float*)d_in[4];
    const float* W2l = (const float*)d_in[5];
    const float* b2l = (const float*)d_in[6];
    const float* W2r = (const float*)d_in[7];
    const float* Wf1 = (const float*)d_in[8];
    const float* bf1 = (const float*)d_in[9];
    const float* Wf2 = (const float*)d_in[10];
    const float* bf2 = (const float*)d_in[11];
    float* out = (float*)d_out;

    const int* src = ei;            // edge_index[0]
    const int* dst = ei + NE;       // edge_index[1]

    char* ws = (char*)d_ws;
    size_t off = 0;
    auto alloc = [&](size_t bytes) {
        char* p = ws + off;
        off = (off + bytes + 255) & ~(size_t)255;
        return p;
    };
    int* hist      = (int*)alloc((size_t)NN * sizeof(int));
    int* rowBeg    = (int*)alloc((size_t)NN * sizeof(int));
    int* cursor    = (int*)alloc((size_t)NN * sizeof(int));
    int* partials  = (int*)alloc(128 * sizeof(int));
    int* pscan     = (int*)alloc(128 * sizeof(int));
    int* sortedSrc = (int*)alloc((size_t)NE * sizeof(int));
    float* h1      = (float*)alloc((size_t)NN * D * sizeof(float));

    dim3 blk(256);

    // ---- CSR build (shared by both layers) ----
    hipMemsetAsync(hist, 0, (size_t)NN * sizeof(int), stream);
    hist_kernel<<<2048, blk, 0, stream>>>(dst, hist, NE);
    block_sum_kernel<<<NBLK_SCAN, blk, 0, stream>>>(hist, partials, NN);
    scan_partials_kernel<<<1, 128, 0, stream>>>(partials, pscan, NBLK_SCAN);
    scan_chunk_kernel<<<NBLK_SCAN, blk, 0, stream>>>(hist, pscan, rowBeg, cursor, NN);
    fill_kernel<<<2048, blk, 0, stream>>>(src, dst, cursor, sortedSrc, NE);

    // ---- fused layers ----
    sage_layer1_kernel<<<1024, dim3(512), 0, stream>>>(
        x, rowBeg, hist, sortedSrc, W1l, b1l, W1r, h1, NPAIR);
    sage_layer2_mlp_kernel<<<1024, dim3(512), 0, stream>>>(
        h1, rowBeg, hist, sortedSrc, W2l, b2l, W2r,
        Wf1, bf1, Wf2, bf2, out, NPAIR);
}

// Round 5
// 876.564 us; speedup vs baseline: 1.2103x; 1.2103x over previous
//
#include <hip/hip_runtime.h>
#include <math.h>

#define NN 100000
#define NE 1600000
#define NPAIR (NN / 2)
#define D 64
#define DM 32
#define SCAN_CHUNK 1024
#define NBLK_SCAN ((NN + SCAN_CHUNK - 1) / SCAN_CHUNK)   // 98

__device__ __forceinline__ float bcastf(float v, int k) {
    return __uint_as_float(__builtin_amdgcn_readlane(__float_as_uint(v), k));
}
__device__ __forceinline__ int bcasti(int v, int k) {
    return (int)__builtin_amdgcn_readlane((unsigned)v, k);
}

// ---------- CSR build ----------
__global__ __launch_bounds__(256) void hist_kernel(
    const int* __restrict__ dst, int* __restrict__ hist, int nEdges)
{
    for (int e = blockIdx.x * 256 + threadIdx.x; e < nEdges; e += gridDim.x * 256)
        atomicAdd(&hist[dst[e]], 1);
}

__global__ __launch_bounds__(256) void block_sum_kernel(
    const int* __restrict__ hist, int* __restrict__ partials, int n)
{
    __shared__ int red[256];
    int t = threadIdx.x;
    int base = blockIdx.x * SCAN_CHUNK + t * 4;
    int tot = 0;
#pragma unroll
    for (int k = 0; k < 4; ++k)
        if (base + k < n) tot += hist[base + k];
    red[t] = tot;
    __syncthreads();
    for (int off = 128; off >= 1; off >>= 1) {
        if (t < off) red[t] += red[t + off];
        __syncthreads();
    }
    if (t == 0) partials[blockIdx.x] = red[0];
}

__global__ __launch_bounds__(128) void scan_partials_kernel(
    const int* __restrict__ partials, int* __restrict__ pscan, int nb)
{
    __shared__ int l[128];
    int t = threadIdx.x;
    if (t < nb) l[t] = partials[t];
    __syncthreads();
    if (t == 0) {
        int run = 0;
        for (int i = 0; i < nb; ++i) { int tmp = l[i]; l[i] = run; run += tmp; }
    }
    __syncthreads();
    if (t < nb) pscan[t] = l[t];
}

__global__ __launch_bounds__(256) void scan_chunk_kernel(
    const int* __restrict__ hist, const int* __restrict__ pscan,
    int* __restrict__ rowBeg, int* __restrict__ cursor, int n)
{
    __shared__ int lsum[256];
    int t = threadIdx.x;
    int base = blockIdx.x * SCAN_CHUNK + t * 4;
    int v[4];
    int tot = 0;
#pragma unroll
    for (int k = 0; k < 4; ++k) {
        v[k] = (base + k < n) ? hist[base + k] : 0;
        tot += v[k];
    }
    lsum[t] = tot;
    __syncthreads();
    for (int off = 1; off < 256; off <<= 1) {
        int x = (t >= off) ? lsum[t - off] : 0;
        __syncthreads();
        lsum[t] += x;
        __syncthreads();
    }
    int run = pscan[blockIdx.x] + lsum[t] - tot;
#pragma unroll
    for (int k = 0; k < 4; ++k) {
        if (base + k < n) {
            rowBeg[base + k] = run;
            cursor[base + k] = run;
            run += v[k];
        }
    }
}

__global__ __launch_bounds__(256) void fill_kernel(
    const int* __restrict__ src, const int* __restrict__ dst,
    int* __restrict__ cursor, int* __restrict__ sortedSrc, int nEdges)
{
    for (int e = blockIdx.x * 256 + threadIdx.x; e < nEdges; e += gridDim.x * 256) {
        int pos = atomicAdd(&cursor[dst[e]], 1);
        sortedSrc[pos] = src[e];
    }
}

// ---------- gather: sum of h[src] rows over one node's segment ----------
// Whole wave reads one row per edge (256B coalesced); 8 loads in flight.
__device__ __forceinline__ float gather_sum(
    const float* __restrict__ h, const int* __restrict__ ss,
    int beg, int deg, int lane)
{
    float acc = 0.0f;
    for (int c = 0; c < deg; c += 64) {
        int cl = min(64, deg - c);
        int idx = (lane < cl) ? ss[beg + c + lane] : 0;
        int j = 0;
        for (; j + 8 <= cl; j += 8) {
            float v0 = h[(size_t)bcasti(idx, j + 0) * D + lane];
            float v1 = h[(size_t)bcasti(idx, j + 1) * D + lane];
            float v2 = h[(size_t)bcasti(idx, j + 2) * D + lane];
            float v3 = h[(size_t)bcasti(idx, j + 3) * D + lane];
            float v4 = h[(size_t)bcasti(idx, j + 4) * D + lane];
            float v5 = h[(size_t)bcasti(idx, j + 5) * D + lane];
            float v6 = h[(size_t)bcasti(idx, j + 6) * D + lane];
            float v7 = h[(size_t)bcasti(idx, j + 7) * D + lane];
            acc += ((v0 + v1) + (v2 + v3)) + ((v4 + v5) + (v6 + v7));
        }
        for (; j < cl; ++j)
            acc += h[(size_t)bcasti(idx, j) * D + lane];
    }
    return acc;
}

// ---------- fused SAGE layer (2 nodes per wave), optional fused MLP head ----
// Weights in LDS as W^T rows (row j = column j of W), XOR-swizzled chunks:
// chunk c of row j stored at slot c^(j&15) -> bank-optimal b128 reads, 32KB.
template <int WITH_MLP>
__global__ __launch_bounds__(256) void sage_layer_kernel(
    const float* __restrict__ hin,
    const int* __restrict__ rowBeg, const int* __restrict__ deg,
    const int* __restrict__ sortedSrc,
    const float* __restrict__ Wl, const float* __restrict__ bl,
    const float* __restrict__ Wr,
    const float* __restrict__ Wf1, const float* __restrict__ bf1,
    const float* __restrict__ Wf2, const float* __restrict__ bf2,
    float* __restrict__ hout,      // layer output (WITH_MLP=0) or final out (=1)
    int nPair)
{
    __shared__ float sWT[2 * D * D];                    // 32768 B
    __shared__ float sF1T[WITH_MLP ? (DM * D) : 1];     // 8192 B when used
    for (int i = threadIdx.x; i < D * D; i += 256) {
        int k = i >> 6, j = i & 63;                     // W[k][j]
        int addr = j * D + ((((k >> 2) ^ (j & 15)) << 2) | (k & 3));
        sWT[addr] = Wl[i];
        sWT[D * D + addr] = Wr[i];
    }
    if (WITH_MLP) {
        for (int i = threadIdx.x; i < D * DM; i += 256) {
            int k = i >> 5, j = i & 31;                 // Wf1[k][j]
            int addr = j * D + ((((k >> 2) ^ (j & 15)) << 2) | (k & 3));
            sF1T[addr] = Wf1[i];
        }
    }
    __syncthreads();

    int lane = threadIdx.x & 63;
    int wid = threadIdx.x >> 6;
    int sxor = lane & 15;
    const float* rowWl = &sWT[lane * D];
    const float* rowWr = &sWT[D * D + lane * D];

    for (int p = blockIdx.x * 4 + wid; p < nPair; p += gridDim.x * 4) {
        int nA = 2 * p, nB = 2 * p + 1;
        int dgA = deg[nA], dgB = deg[nB];
        float sA = gather_sum(hin, sortedSrc, rowBeg[nA], dgA, lane);
        float sB = gather_sum(hin, sortedSrc, rowBeg[nB], dgB, lane);
        float mA = sA * ((dgA > 0) ? 1.0f / (float)dgA : 0.0f);
        float mB = sB * ((dgB > 0) ? 1.0f / (float)dgB : 0.0f);
        float xA = hin[(size_t)nA * D + lane];
        float xB = hin[(size_t)nB * D + lane];

        float b = bl[lane];
        float accA = b, accB = b;
#pragma unroll
        for (int c = 0; c < 16; ++c) {
            int sl = (c ^ sxor) << 2;
            float4 wl = *(const float4*)&rowWl[sl];
            float4 wr = *(const float4*)&rowWr[sl];
            int k0 = c << 2;
            accA += bcastf(mA, k0 + 0) * wl.x + bcastf(xA, k0 + 0) * wr.x
                  + bcastf(mA, k0 + 1) * wl.y + bcastf(xA, k0 + 1) * wr.y
                  + bcastf(mA, k0 + 2) * wl.z + bcastf(xA, k0 + 2) * wr.z
                  + bcastf(mA, k0 + 3) * wl.w + bcastf(xA, k0 + 3) * wr.w;
            accB += bcastf(mB, k0 + 0) * wl.x + bcastf(xB, k0 + 0) * wr.x
                  + bcastf(mB, k0 + 1) * wl.y + bcastf(xB, k0 + 1) * wr.y
                  + bcastf(mB, k0 + 2) * wl.z + bcastf(xB, k0 + 2) * wr.z
                  + bcastf(mB, k0 + 3) * wl.w + bcastf(xB, k0 + 3) * wr.w;
        }

        if (!WITH_MLP) {
            hout[(size_t)nA * D + lane] = fmaxf(accA, 0.0f);
            hout[(size_t)nB * D + lane] = fmaxf(accB, 0.0f);
        } else {
            float h2A = fmaxf(accA, 0.0f);
            float h2B = fmaxf(accB, 0.0f);
            bool lo = (lane < 32);
            const float* rowF1 = &sF1T[(lane & 31) * D];
            float acc2 = bf1[lane & 31];
#pragma unroll
            for (int c = 0; c < 16; ++c) {
                int sl = (c ^ sxor) << 2;
                float4 f1 = *(const float4*)&rowF1[sl];
                int k0 = c << 2;
                float a0 = lo ? bcastf(h2A, k0 + 0) : bcastf(h2B, k0 + 0);
                float a1 = lo ? bcastf(h2A, k0 + 1) : bcastf(h2B, k0 + 1);
                float a2 = lo ? bcastf(h2A, k0 + 2) : bcastf(h2B, k0 + 2);
                float a3 = lo ? bcastf(h2A, k0 + 3) : bcastf(h2B, k0 + 3);
                acc2 += a0 * f1.x + a1 * f1.y + a2 * f1.z + a3 * f1.w;
            }
            float pv = fmaxf(acc2, 0.0f) * Wf2[lane & 31];
#pragma unroll
            for (int off = 16; off >= 1; off >>= 1) pv += __shfl_xor(pv, off);
            if (lane == 0)
                hout[nA] = 1.0f / (1.0f + expf(-(pv + bf2[0])));
            if (lane == 32)
                hout[nB] = 1.0f / (1.0f + expf(-(pv + bf2[0])));
        }
    }
}

extern "C" void kernel_launch(void* const* d_in, const int* in_sizes, int n_in,
                              void* d_out, int out_size, void* d_ws, size_t ws_size,
                              hipStream_t stream)
{
    const float* x   = (const float*)d_in[0];
    const int*   ei  = (const int*)d_in[1];
    const float* W1l = (const float*)d_in[2];
    const float* b1l = (const float*)d_in[3];
    const float* W1r = (const float*)d_in[4];
    const float* W2l = (const float*)d_in[5];
    const float* b2l = (const float*)d_in[6];
    const float* W2r = (const float*)d_in[7];
    const float* Wf1 = (const float*)d_in[8];
    const float* bf1 = (const float*)d_in[9];
    const float* Wf2 = (const float*)d_in[10];
    const float* bf2 = (const float*)d_in[11];
    float* out = (float*)d_out;

    const int* src = ei;            // edge_index[0]
    const int* dst = ei + NE;       // edge_index[1]

    char* ws = (char*)d_ws;
    size_t off = 0;
    auto alloc = [&](size_t bytes) {
        char* p = ws + off;
        off = (off + bytes + 255) & ~(size_t)255;
        return p;
    };
    int* hist      = (int*)alloc((size_t)NN * sizeof(int));
    int* rowBeg    = (int*)alloc((size_t)NN * sizeof(int));
    int* cursor    = (int*)alloc((size_t)NN * sizeof(int));
    int* partials  = (int*)alloc(128 * sizeof(int));
    int* pscan     = (int*)alloc(128 * sizeof(int));
    int* sortedSrc = (int*)alloc((size_t)NE * sizeof(int));
    float* h1      = (float*)alloc((size_t)NN * D * sizeof(float));

    dim3 blk(256);

    // ---- CSR build (shared by both layers) ----
    hipMemsetAsync(hist, 0, (size_t)NN * sizeof(int), stream);
    hist_kernel<<<2048, blk, 0, stream>>>(dst, hist, NE);
    block_sum_kernel<<<NBLK_SCAN, blk, 0, stream>>>(hist, partials, NN);
    scan_partials_kernel<<<1, 128, 0, stream>>>(partials, pscan, NBLK_SCAN);
    scan_chunk_kernel<<<NBLK_SCAN, blk, 0, stream>>>(hist, pscan, rowBeg, cursor, NN);
    fill_kernel<<<2048, blk, 0, stream>>>(src, dst, cursor, sortedSrc, NE);

    // ---- layer 1 (no MLP) ----
    sage_layer_kernel<0><<<2048, blk, 0, stream>>>(
        x, rowBeg, hist, sortedSrc, W1l, b1l, W1r,
        Wf1, bf1, Wf2, bf2, h1, NPAIR);

    // ---- layer 2 + fused MLP head ----
    sage_layer_kernel<1><<<2048, blk, 0, stream>>>(
        h1, rowBeg, hist, sortedSrc, W2l, b2l, W2r,
        Wf1, bf1, Wf2, bf2, out, NPAIR);
}

// Round 7
// 793.637 us; speedup vs baseline: 1.3368x; 1.1045x over previous
//
#include <hip/hip_runtime.h>
#include <math.h>

#define NN 100000
#define NE 1600000
#define D 64
#define DM 32
#define SCAN_CHUNK 1024
#define NBLK_SCAN ((NN + SCAN_CHUNK - 1) / SCAN_CHUNK)   // 98

__device__ __forceinline__ float bcastf(float v, int k) {
    // NOTE: k MUST be wave-uniform (v_readlane takes an SGPR index).
    return __uint_as_float(__builtin_amdgcn_readlane(__float_as_uint(v), k));
}
__device__ __forceinline__ int bcasti(int v, int k) {
    return (int)__builtin_amdgcn_readlane((unsigned)v, k);
}

// ---------- CSR build ----------
__global__ __launch_bounds__(256) void hist_kernel(
    const int* __restrict__ dst, int* __restrict__ hist, int nEdges)
{
    for (int e = blockIdx.x * 256 + threadIdx.x; e < nEdges; e += gridDim.x * 256)
        atomicAdd(&hist[dst[e]], 1);
}

__global__ __launch_bounds__(256) void block_sum_kernel(
    const int* __restrict__ hist, int* __restrict__ partials, int n)
{
    __shared__ int red[256];
    int t = threadIdx.x;
    int base = blockIdx.x * SCAN_CHUNK + t * 4;
    int tot = 0;
#pragma unroll
    for (int k = 0; k < 4; ++k)
        if (base + k < n) tot += hist[base + k];
    red[t] = tot;
    __syncthreads();
    for (int off = 128; off >= 1; off >>= 1) {
        if (t < off) red[t] += red[t + off];
        __syncthreads();
    }
    if (t == 0) partials[blockIdx.x] = red[0];
}

__global__ __launch_bounds__(128) void scan_partials_kernel(
    const int* __restrict__ partials, int* __restrict__ pscan, int nb)
{
    __shared__ int l[128];
    int t = threadIdx.x;
    if (t < nb) l[t] = partials[t];
    __syncthreads();
    if (t == 0) {
        int run = 0;
        for (int i = 0; i < nb; ++i) { int tmp = l[i]; l[i] = run; run += tmp; }
    }
    __syncthreads();
    if (t < nb) pscan[t] = l[t];
}

__global__ __launch_bounds__(256) void scan_chunk_kernel(
    const int* __restrict__ hist, const int* __restrict__ pscan,
    int* __restrict__ rowBeg, int* __restrict__ cursor, int n)
{
    __shared__ int lsum[256];
    int t = threadIdx.x;
    int base = blockIdx.x * SCAN_CHUNK + t * 4;
    int v[4];
    int tot = 0;
#pragma unroll
    for (int k = 0; k < 4; ++k) {
        v[k] = (base + k < n) ? hist[base + k] : 0;
        tot += v[k];
    }
    lsum[t] = tot;
    __syncthreads();
    for (int off = 1; off < 256; off <<= 1) {
        int x = (t >= off) ? lsum[t - off] : 0;
        __syncthreads();
        lsum[t] += x;
        __syncthreads();
    }
    int run = pscan[blockIdx.x] + lsum[t] - tot;
#pragma unroll
    for (int k = 0; k < 4; ++k) {
        if (base + k < n) {
            rowBeg[base + k] = run;
            cursor[base + k] = run;
            run += v[k];
        }
    }
}

__global__ __launch_bounds__(256) void fill_kernel(
    const int* __restrict__ src, const int* __restrict__ dst,
    int* __restrict__ cursor, int* __restrict__ sortedSrc, int nEdges)
{
    for (int e = blockIdx.x * 256 + threadIdx.x; e < nEdges; e += gridDim.x * 256) {
        int pos = atomicAdd(&cursor[dst[e]], 1);
        sortedSrc[pos] = src[e];
    }
}

// ---------- gather: sum of h[src] rows over one node's segment ----------
// Whole wave reads one row per edge (256B coalesced); 8 loads in flight.
__device__ __forceinline__ float gather_sum(
    const float* __restrict__ h, const int* __restrict__ ss,
    int beg, int deg, int lane)
{
    float acc = 0.0f;
    for (int c = 0; c < deg; c += 64) {
        int cl = min(64, deg - c);
        int idx = (lane < cl) ? ss[beg + c + lane] : 0;
        int j = 0;
        for (; j + 8 <= cl; j += 8) {
            float v0 = h[(size_t)bcasti(idx, j + 0) * D + lane];
            float v1 = h[(size_t)bcasti(idx, j + 1) * D + lane];
            float v2 = h[(size_t)bcasti(idx, j + 2) * D + lane];
            float v3 = h[(size_t)bcasti(idx, j + 3) * D + lane];
            float v4 = h[(size_t)bcasti(idx, j + 4) * D + lane];
            float v5 = h[(size_t)bcasti(idx, j + 5) * D + lane];
            float v6 = h[(size_t)bcasti(idx, j + 6) * D + lane];
            float v7 = h[(size_t)bcasti(idx, j + 7) * D + lane];
            acc += ((v0 + v1) + (v2 + v3)) + ((v4 + v5) + (v6 + v7));
        }
        for (; j < cl; ++j)
            acc += h[(size_t)bcasti(idx, j) * D + lane];
    }
    return acc;
}

// ---------- fused SAGE layer (1 node per wave), optional fused MLP head ----
// Weights in LDS as W^T rows, XOR-swizzled chunks: chunk c of row j at slot
// c^(j&15) -> bank-friendly b128 reads, no padding (32KB for Wl+Wr).
template <int WITH_MLP>
__global__ __launch_bounds__(256, 4) void sage_layer_kernel(
    const float* __restrict__ hin,
    const int* __restrict__ rowBeg, const int* __restrict__ deg,
    const int* __restrict__ sortedSrc,
    const float* __restrict__ Wl, const float* __restrict__ bl,
    const float* __restrict__ Wr,
    const float* __restrict__ Wf1, const float* __restrict__ bf1,
    const float* __restrict__ Wf2, const float* __restrict__ bf2,
    float* __restrict__ hout,      // layer output (WITH_MLP=0) or final out (=1)
    int n)
{
    __shared__ float sWT[2 * D * D];                    // 32768 B
    __shared__ float sF1T[WITH_MLP ? (DM * D) : 1];     // 8192 B when used
    for (int i = threadIdx.x; i < D * D; i += 256) {
        int k = i >> 6, j = i & 63;                     // W[k][j]
        int addr = j * D + ((((k >> 2) ^ (j & 15)) << 2) | (k & 3));
        sWT[addr] = Wl[i];
        sWT[D * D + addr] = Wr[i];
    }
    if (WITH_MLP) {
        for (int i = threadIdx.x; i < D * DM; i += 256) {
            int k = i >> 5, j = i & 31;                 // Wf1[k][j]
            int addr = j * D + ((((k >> 2) ^ (j & 15)) << 2) | (k & 3));
            sF1T[addr] = Wf1[i];
        }
    }
    __syncthreads();

    int lane = threadIdx.x & 63;
    int wid = threadIdx.x >> 6;
    int sxor = lane & 15;
    const float* rowWl = &sWT[lane * D];
    const float* rowWr = &sWT[D * D + lane * D];
    const float* rowF1 = &sF1T[(lane & 31) * D];

    // hoist all loop-invariant small loads
    float biasMain = bl[lane];
    float f1bias = 0.f, f2w = 0.f, bias2 = 0.f;
    if (WITH_MLP) {
        f1bias = bf1[lane & 31];
        f2w    = Wf2[lane & 31];
        bias2  = bf2[0];
    }

    for (int node = blockIdx.x * 4 + wid; node < n; node += gridDim.x * 4) {
        int dg = deg[node];
        float s = gather_sum(hin, sortedSrc, rowBeg[node], dg, lane);
        float m = s * ((dg > 0) ? 1.0f / (float)dg : 0.0f);
        float x = hin[(size_t)node * D + lane];

        float acc = biasMain;
#pragma unroll
        for (int c = 0; c < 16; ++c) {
            int sl = (c ^ sxor) << 2;
            float4 wl = *(const float4*)&rowWl[sl];
            float4 wr = *(const float4*)&rowWr[sl];
            int k0 = c << 2;
            acc += bcastf(m, k0 + 0) * wl.x + bcastf(x, k0 + 0) * wr.x
                 + bcastf(m, k0 + 1) * wl.y + bcastf(x, k0 + 1) * wr.y
                 + bcastf(m, k0 + 2) * wl.z + bcastf(x, k0 + 2) * wr.z
                 + bcastf(m, k0 + 3) * wl.w + bcastf(x, k0 + 3) * wr.w;
        }

        if (!WITH_MLP) {
            hout[(size_t)node * D + lane] = fmaxf(acc, 0.0f);
        } else {
            float h2 = fmaxf(acc, 0.0f);
            // h3[j] = relu(bf1[j] + sum_k h2[k]*Wf1[k][j]), j = lane&31.
            // Both wave halves compute the same 32 outputs redundantly —
            // readlane index k stays wave-uniform (divergent index is UB).
            float acc2 = 0.0f;
#pragma unroll
            for (int c = 0; c < 16; ++c) {
                int sl = (c ^ sxor) << 2;
                float4 f1 = *(const float4*)&rowF1[sl];
                int k0 = c << 2;
                acc2 += bcastf(h2, k0 + 0) * f1.x + bcastf(h2, k0 + 1) * f1.y
                      + bcastf(h2, k0 + 2) * f1.z + bcastf(h2, k0 + 3) * f1.w;
            }
            float pv = fmaxf(acc2 + f1bias, 0.0f) * f2w;   // h3[j] * Wf2[j]
#pragma unroll
            for (int off = 16; off >= 1; off >>= 1) pv += __shfl_xor(pv, off);
            if (lane == 0)
                hout[node] = 1.0f / (1.0f + expf(-(pv + bias2)));
        }
    }
}

extern "C" void kernel_launch(void* const* d_in, const int* in_sizes, int n_in,
                              void* d_out, int out_size, void* d_ws, size_t ws_size,
                              hipStream_t stream)
{
    const float* x   = (const float*)d_in[0];
    const int*   ei  = (const int*)d_in[1];
    const float* W1l = (const float*)d_in[2];
    const float* b1l = (const float*)d_in[3];
    const float* W1r = (const float*)d_in[4];
    const float* W2l = (const float*)d_in[5];
    const float* b2l = (const float*)d_in[6];
    const float* W2r = (const float*)d_in[7];
    const float* Wf1 = (const float*)d_in[8];
    const float* bf1 = (const float*)d_in[9];
    const float* Wf2 = (const float*)d_in[10];
    const float* bf2 = (const float*)d_in[11];
    float* out = (float*)d_out;

    const int* src = ei;            // edge_index[0]
    const int* dst = ei + NE;       // edge_index[1]

    char* ws = (char*)d_ws;
    size_t off = 0;
    auto alloc = [&](size_t bytes) {
        char* p = ws + off;
        off = (off + bytes + 255) & ~(size_t)255;
        return p;
    };
    int* hist      = (int*)alloc((size_t)NN * sizeof(int));
    int* rowBeg    = (int*)alloc((size_t)NN * sizeof(int));
    int* cursor    = (int*)alloc((size_t)NN * sizeof(int));
    int* partials  = (int*)alloc(128 * sizeof(int));
    int* pscan     = (int*)alloc(128 * sizeof(int));
    int* sortedSrc = (int*)alloc((size_t)NE * sizeof(int));
    float* h1      = (float*)alloc((size_t)NN * D * sizeof(float));

    dim3 blk(256);

    // ---- CSR build (shared by both layers) ----
    hipMemsetAsync(hist, 0, (size_t)NN * sizeof(int), stream);
    hist_kernel<<<2048, blk, 0, stream>>>(dst, hist, NE);
    block_sum_kernel<<<NBLK_SCAN, blk, 0, stream>>>(hist, partials, NN);
    scan_partials_kernel<<<1, 128, 0, stream>>>(partials, pscan, NBLK_SCAN);
    scan_chunk_kernel<<<NBLK_SCAN, blk, 0, stream>>>(hist, pscan, rowBeg, cursor, NN);
    fill_kernel<<<2048, blk, 0, stream>>>(src, dst, cursor, sortedSrc, NE);

    // ---- layer 1 (no MLP) ----
    sage_layer_kernel<0><<<1024, blk, 0, stream>>>(
        x, rowBeg, hist, sortedSrc, W1l, b1l, W1r,
        Wf1, bf1, Wf2, bf2, h1, NN);

    // ---- layer 2 + fused MLP head ----
    sage_layer_kernel<1><<<1024, blk, 0, stream>>>(
        h1, rowBeg, hist, sortedSrc, W2l, b2l, W2r,
        Wf1, bf1, Wf2, bf2, out, NN);
}

// Round 8
// 619.469 us; speedup vs baseline: 1.7126x; 1.2812x over previous
//
#include <hip/hip_runtime.h>
#include <math.h>

#define NN 100000
#define NE 1600000
#define D 64
#define DM 32
#define PAD 68            // padded row stride (floats) for transposed weights in LDS
#define SCAN_CHUNK 1024
#define NBLK_SCAN ((NN + SCAN_CHUNK - 1) / SCAN_CHUNK)   // 98

__device__ __forceinline__ float bcastf(float v, int k) {
    // k MUST be wave-uniform (v_readlane takes an SGPR index).
    return __uint_as_float(__builtin_amdgcn_readlane(__float_as_uint(v), k));
}
__device__ __forceinline__ int bcasti(int v, int k) {
    return (int)__builtin_amdgcn_readlane((unsigned)v, k);
}
__device__ __forceinline__ unsigned short f2bf(float f) {
    unsigned u = __float_as_uint(f);
    unsigned r = (u + 0x7FFF + ((u >> 16) & 1)) >> 16;   // round-nearest-even
    return (unsigned short)r;
}
__device__ __forceinline__ float bf2f(unsigned short b) {
    return __uint_as_float(((unsigned)b) << 16);
}

// ---------- fp32 -> bf16 conversion (vectorized) ----------
__global__ __launch_bounds__(256) void cvt_bf16_kernel(
    const float4* __restrict__ in, ushort4* __restrict__ outb, int n4)
{
    for (int i = blockIdx.x * 256 + threadIdx.x; i < n4; i += gridDim.x * 256) {
        float4 v = in[i];
        ushort4 o;
        o.x = f2bf(v.x); o.y = f2bf(v.y); o.z = f2bf(v.z); o.w = f2bf(v.w);
        outb[i] = o;
    }
}

// ---------- CSR build ----------
__global__ __launch_bounds__(256) void hist_kernel(
    const int* __restrict__ dst, int* __restrict__ hist, int nEdges)
{
    for (int e = blockIdx.x * 256 + threadIdx.x; e < nEdges; e += gridDim.x * 256)
        atomicAdd(&hist[dst[e]], 1);
}

__global__ __launch_bounds__(256) void block_sum_kernel(
    const int* __restrict__ hist, int* __restrict__ partials, int n)
{
    __shared__ int red[256];
    int t = threadIdx.x;
    int base = blockIdx.x * SCAN_CHUNK + t * 4;
    int tot = 0;
#pragma unroll
    for (int k = 0; k < 4; ++k)
        if (base + k < n) tot += hist[base + k];
    red[t] = tot;
    __syncthreads();
    for (int off = 128; off >= 1; off >>= 1) {
        if (t < off) red[t] += red[t + off];
        __syncthreads();
    }
    if (t == 0) partials[blockIdx.x] = red[0];
}

__global__ __launch_bounds__(128) void scan_partials_kernel(
    const int* __restrict__ partials, int* __restrict__ pscan, int nb)
{
    __shared__ int l[128];
    int t = threadIdx.x;
    if (t < nb) l[t] = partials[t];
    __syncthreads();
    if (t == 0) {
        int run = 0;
        for (int i = 0; i < nb; ++i) { int tmp = l[i]; l[i] = run; run += tmp; }
    }
    __syncthreads();
    if (t < nb) pscan[t] = l[t];
}

__global__ __launch_bounds__(256) void scan_chunk_kernel(
    const int* __restrict__ hist, const int* __restrict__ pscan,
    int* __restrict__ rowBeg, int* __restrict__ cursor, int n)
{
    __shared__ int lsum[256];
    int t = threadIdx.x;
    int base = blockIdx.x * SCAN_CHUNK + t * 4;
    int v[4];
    int tot = 0;
#pragma unroll
    for (int k = 0; k < 4; ++k) {
        v[k] = (base + k < n) ? hist[base + k] : 0;
        tot += v[k];
    }
    lsum[t] = tot;
    __syncthreads();
    for (int off = 1; off < 256; off <<= 1) {
        int x = (t >= off) ? lsum[t - off] : 0;
        __syncthreads();
        lsum[t] += x;
        __syncthreads();
    }
    int run = pscan[blockIdx.x] + lsum[t] - tot;
#pragma unroll
    for (int k = 0; k < 4; ++k) {
        if (base + k < n) {
            rowBeg[base + k] = run;
            cursor[base + k] = run;
            run += v[k];
        }
    }
}

__global__ __launch_bounds__(256) void fill_kernel(
    const int* __restrict__ src, const int* __restrict__ dst,
    int* __restrict__ cursor, int* __restrict__ sortedSrc, int nEdges)
{
    for (int e = blockIdx.x * 256 + threadIdx.x; e < nEdges; e += gridDim.x * 256) {
        int pos = atomicAdd(&cursor[dst[e]], 1);
        sortedSrc[pos] = src[e];
    }
}

// ---------- gather: sum of bf16 h[src] rows over one node's segment ----------
// Whole wave reads one row per edge (128B coalesced); 4 loads in flight (R3 depth).
__device__ __forceinline__ float gather_sum_bf(
    const unsigned short* __restrict__ hb, const int* __restrict__ ss,
    int beg, int deg, int lane)
{
    float acc = 0.0f;
    for (int c = 0; c < deg; c += 64) {
        int cl = min(64, deg - c);
        int idx = (lane < cl) ? ss[beg + c + lane] : 0;
        int j = 0;
        for (; j + 4 <= cl; j += 4) {
            unsigned short u0 = hb[(size_t)bcasti(idx, j + 0) * D + lane];
            unsigned short u1 = hb[(size_t)bcasti(idx, j + 1) * D + lane];
            unsigned short u2 = hb[(size_t)bcasti(idx, j + 2) * D + lane];
            unsigned short u3 = hb[(size_t)bcasti(idx, j + 3) * D + lane];
            acc += (bf2f(u0) + bf2f(u1)) + (bf2f(u2) + bf2f(u3));
        }
        for (; j < cl; ++j)
            acc += bf2f(hb[(size_t)bcasti(idx, j) * D + lane]);
    }
    return acc;
}

// ---------- fused SAGE layer (1 node per wave; R3-proven config) ----------
// Weights in LDS as W^T rows (row j = column j of W), PAD=68 stride.
// WITH_MLP=0: root from fp32 x, output bf16 h1b.  WITH_MLP=1: root from bf16
// h1b, fused MLP head, scalar sigmoid output.
template <int WITH_MLP>
__global__ __launch_bounds__(256) void sage_layer_kernel(
    const float* __restrict__ rootf,
    const unsigned short* __restrict__ hinb,
    const int* __restrict__ rowBeg, const int* __restrict__ deg,
    const int* __restrict__ sortedSrc,
    const float* __restrict__ Wl, const float* __restrict__ bl,
    const float* __restrict__ Wr,
    const float* __restrict__ Wf1, const float* __restrict__ bf1,
    const float* __restrict__ Wf2, const float* __restrict__ bf2,
    unsigned short* __restrict__ houtb,   // bf16 layer output (WITH_MLP=0)
    float* __restrict__ outp,             // final output (WITH_MLP=1)
    int n)
{
    __shared__ float sWlT[D * PAD];
    __shared__ float sWrT[D * PAD];
    __shared__ float sF1T[WITH_MLP ? (DM * PAD) : 1];
    for (int i = threadIdx.x; i < D * D; i += 256) {
        int k = i >> 6, j = i & 63;                      // W[k][j]
        sWlT[j * PAD + k] = Wl[i];
        sWrT[j * PAD + k] = Wr[i];
    }
    if (WITH_MLP) {
        for (int i = threadIdx.x; i < D * DM; i += 256) {
            int k = i >> 5, j = i & 31;                  // Wf1[k][j]
            sF1T[j * PAD + k] = Wf1[i];
        }
    }
    __syncthreads();

    int lane = threadIdx.x & 63;
    int wid = threadIdx.x >> 6;
    const float* rowWl = &sWlT[lane * PAD];
    const float* rowWr = &sWrT[lane * PAD];
    const float* rowF1 = &sF1T[(lane & 31) * PAD];

    // hoist loop-invariant global loads
    float biasMain = bl[lane];
    float f1bias = 0.f, f2w = 0.f, bias2 = 0.f;
    if (WITH_MLP) {
        f1bias = bf1[lane & 31];
        f2w    = Wf2[lane & 31];
        bias2  = bf2[0];
    }

    for (int node = blockIdx.x * 4 + wid; node < n; node += gridDim.x * 4) {
        int dg = deg[node];
        float s = gather_sum_bf(hinb, sortedSrc, rowBeg[node], dg, lane);
        float m = s * ((dg > 0) ? 1.0f / (float)dg : 0.0f);
        float x = WITH_MLP ? bf2f(hinb[(size_t)node * D + lane])
                           : rootf[(size_t)node * D + lane];

        float acc = biasMain;
#pragma unroll
        for (int k0 = 0; k0 < D; k0 += 4) {
            float4 wl = *(const float4*)&rowWl[k0];
            float4 wr = *(const float4*)&rowWr[k0];
            acc += bcastf(m, k0 + 0) * wl.x + bcastf(x, k0 + 0) * wr.x
                 + bcastf(m, k0 + 1) * wl.y + bcastf(x, k0 + 1) * wr.y
                 + bcastf(m, k0 + 2) * wl.z + bcastf(x, k0 + 2) * wr.z
                 + bcastf(m, k0 + 3) * wl.w + bcastf(x, k0 + 3) * wr.w;
        }

        if (!WITH_MLP) {
            houtb[(size_t)node * D + lane] = f2bf(fmaxf(acc, 0.0f));
        } else {
            float h2 = fmaxf(acc, 0.0f);
            // h3[j] = relu(bf1[j] + sum_k h2[k]*Wf1[k][j]), j = lane (<32).
            // readlane index stays wave-uniform; upper half idles (safe form).
            float acc2 = (lane < DM) ? f1bias : 0.0f;
#pragma unroll
            for (int k0 = 0; k0 < D; k0 += 4) {
                float4 f1 = *(const float4*)&rowF1[k0];
                float a0 = bcastf(h2, k0 + 0);
                float a1 = bcastf(h2, k0 + 1);
                float a2 = bcastf(h2, k0 + 2);
                float a3 = bcastf(h2, k0 + 3);
                if (lane < DM)
                    acc2 += a0 * f1.x + a1 * f1.y + a2 * f1.z + a3 * f1.w;
            }
            float pv = (lane < DM) ? fmaxf(acc2, 0.0f) * f2w : 0.0f;
#pragma unroll
            for (int off = 32; off >= 1; off >>= 1) pv += __shfl_xor(pv, off);
            if (lane == 0)
                outp[node] = 1.0f / (1.0f + expf(-(pv + bias2)));
        }
    }
}

extern "C" void kernel_launch(void* const* d_in, const int* in_sizes, int n_in,
                              void* d_out, int out_size, void* d_ws, size_t ws_size,
                              hipStream_t stream)
{
    const float* x   = (const float*)d_in[0];
    const int*   ei  = (const int*)d_in[1];
    const float* W1l = (const float*)d_in[2];
    const float* b1l = (const float*)d_in[3];
    const float* W1r = (const float*)d_in[4];
    const float* W2l = (const float*)d_in[5];
    const float* b2l = (const float*)d_in[6];
    const float* W2r = (const float*)d_in[7];
    const float* Wf1 = (const float*)d_in[8];
    const float* bf1 = (const float*)d_in[9];
    const float* Wf2 = (const float*)d_in[10];
    const float* bf2 = (const float*)d_in[11];
    float* out = (float*)d_out;

    const int* src = ei;            // edge_index[0]
    const int* dst = ei + NE;       // edge_index[1]

    char* ws = (char*)d_ws;
    size_t off = 0;
    auto alloc = [&](size_t bytes) {
        char* p = ws + off;
        off = (off + bytes + 255) & ~(size_t)255;
        return p;
    };
    int* hist      = (int*)alloc((size_t)NN * sizeof(int));
    int* rowBeg    = (int*)alloc((size_t)NN * sizeof(int));
    int* cursor    = (int*)alloc((size_t)NN * sizeof(int));
    int* partials  = (int*)alloc(128 * sizeof(int));
    int* pscan     = (int*)alloc(128 * sizeof(int));
    int* sortedSrc = (int*)alloc((size_t)NE * sizeof(int));
    unsigned short* xb  = (unsigned short*)alloc((size_t)NN * D * sizeof(unsigned short));
    unsigned short* h1b = (unsigned short*)alloc((size_t)NN * D * sizeof(unsigned short));

    dim3 blk(256);

    // ---- x -> bf16 (independent of CSR build) ----
    cvt_bf16_kernel<<<1024, blk, 0, stream>>>(
        (const float4*)x, (ushort4*)xb, NN * D / 4);

    // ---- CSR build (shared by both layers) ----
    hipMemsetAsync(hist, 0, (size_t)NN * sizeof(int), stream);
    hist_kernel<<<2048, blk, 0, stream>>>(dst, hist, NE);
    block_sum_kernel<<<NBLK_SCAN, blk, 0, stream>>>(hist, partials, NN);
    scan_partials_kernel<<<1, 128, 0, stream>>>(partials, pscan, NBLK_SCAN);
    scan_chunk_kernel<<<NBLK_SCAN, blk, 0, stream>>>(hist, pscan, rowBeg, cursor, NN);
    fill_kernel<<<2048, blk, 0, stream>>>(src, dst, cursor, sortedSrc, NE);

    // ---- layer 1: root fp32 x, gather bf16 xb -> bf16 h1b ----
    sage_layer_kernel<0><<<1024, blk, 0, stream>>>(
        x, xb, rowBeg, hist, sortedSrc, W1l, b1l, W1r,
        Wf1, bf1, Wf2, bf2, h1b, nullptr, NN);

    // ---- layer 2 + fused MLP head: root/gather bf16 h1b -> out ----
    sage_layer_kernel<1><<<1024, blk, 0, stream>>>(
        nullptr, h1b, rowBeg, hist, sortedSrc, W2l, b2l, W2r,
        Wf1, bf1, Wf2, bf2, nullptr, out, NN);
}

// Round 9
// 496.328 us; speedup vs baseline: 2.1376x; 1.2481x over previous
//
#include <hip/hip_runtime.h>
#include <math.h>

#define NN 100000
#define NE 1600000
#define D 64
#define DM 32
#define PAD 68            // padded row stride (floats) for transposed weights in LDS
#define SCAN_CHUNK 1024
#define NBLK_SCAN ((NN + SCAN_CHUNK - 1) / SCAN_CHUNK)   // 98

typedef unsigned int uint32;

__device__ __forceinline__ float bcastf(float v, int k) {
    // k MUST be wave-uniform (v_readlane takes an SGPR index).
    return __uint_as_float(__builtin_amdgcn_readlane(__float_as_uint(v), k));
}
__device__ __forceinline__ int bcasti(int v, int k) {
    return (int)__builtin_amdgcn_readlane((unsigned)v, k);
}
__device__ __forceinline__ unsigned short f2bf(float f) {
    unsigned u = __float_as_uint(f);
    unsigned r = (u + 0x7FFF + ((u >> 16) & 1)) >> 16;   // round-nearest-even
    return (unsigned short)r;
}
__device__ __forceinline__ float bf2f(unsigned short b) {
    return __uint_as_float(((unsigned)b) << 16);
}
__device__ __forceinline__ float bfLo(uint32 u) { return __uint_as_float(u << 16); }
__device__ __forceinline__ float bfHi(uint32 u) { return __uint_as_float(u & 0xFFFF0000u); }

// ---------- fp32 -> bf16 conversion (vectorized) ----------
__global__ __launch_bounds__(256) void cvt_bf16_kernel(
    const float4* __restrict__ in, ushort4* __restrict__ outb, int n4)
{
    for (int i = blockIdx.x * 256 + threadIdx.x; i < n4; i += gridDim.x * 256) {
        float4 v = in[i];
        ushort4 o;
        o.x = f2bf(v.x); o.y = f2bf(v.y); o.z = f2bf(v.z); o.w = f2bf(v.w);
        outb[i] = o;
    }
}

// ---------- CSR build ----------
__global__ __launch_bounds__(256) void hist_kernel(
    const int* __restrict__ dst, int* __restrict__ hist, int nEdges)
{
    for (int e = blockIdx.x * 256 + threadIdx.x; e < nEdges; e += gridDim.x * 256)
        atomicAdd(&hist[dst[e]], 1);
}

__global__ __launch_bounds__(256) void block_sum_kernel(
    const int* __restrict__ hist, int* __restrict__ partials, int n)
{
    __shared__ int red[256];
    int t = threadIdx.x;
    int base = blockIdx.x * SCAN_CHUNK + t * 4;
    int tot = 0;
#pragma unroll
    for (int k = 0; k < 4; ++k)
        if (base + k < n) tot += hist[base + k];
    red[t] = tot;
    __syncthreads();
    for (int off = 128; off >= 1; off >>= 1) {
        if (t < off) red[t] += red[t + off];
        __syncthreads();
    }
    if (t == 0) partials[blockIdx.x] = red[0];
}

__global__ __launch_bounds__(128) void scan_partials_kernel(
    const int* __restrict__ partials, int* __restrict__ pscan, int nb)
{
    __shared__ int l[128];
    int t = threadIdx.x;
    if (t < nb) l[t] = partials[t];
    __syncthreads();
    if (t == 0) {
        int run = 0;
        for (int i = 0; i < nb; ++i) { int tmp = l[i]; l[i] = run; run += tmp; }
    }
    __syncthreads();
    if (t < nb) pscan[t] = l[t];
}

__global__ __launch_bounds__(256) void scan_chunk_kernel(
    const int* __restrict__ hist, const int* __restrict__ pscan,
    int* __restrict__ rowBeg, int* __restrict__ cursor, int n)
{
    __shared__ int lsum[256];
    int t = threadIdx.x;
    int base = blockIdx.x * SCAN_CHUNK + t * 4;
    int v[4];
    int tot = 0;
#pragma unroll
    for (int k = 0; k < 4; ++k) {
        v[k] = (base + k < n) ? hist[base + k] : 0;
        tot += v[k];
    }
    lsum[t] = tot;
    __syncthreads();
    for (int off = 1; off < 256; off <<= 1) {
        int x = (t >= off) ? lsum[t - off] : 0;
        __syncthreads();
        lsum[t] += x;
        __syncthreads();
    }
    int run = pscan[blockIdx.x] + lsum[t] - tot;
#pragma unroll
    for (int k = 0; k < 4; ++k) {
        if (base + k < n) {
            rowBeg[base + k] = run;
            cursor[base + k] = run;
            run += v[k];
        }
    }
}

__global__ __launch_bounds__(256) void fill_kernel(
    const int* __restrict__ src, const int* __restrict__ dst,
    int* __restrict__ cursor, int* __restrict__ sortedSrc, int nEdges)
{
    for (int e = blockIdx.x * 256 + threadIdx.x; e < nEdges; e += gridDim.x * 256) {
        int pos = atomicAdd(&cursor[dst[e]], 1);
        sortedSrc[pos] = src[e];
    }
}

// ---------- lean gather-mean kernel (no LDS; high occupancy) ----------
// One wave per node. Edge pair per load: lanes 0-31 read edge 2p's bf16 row
// (uint = 2 features/lane), lanes 32-63 edge 2p+1 -> 256B per instruction.
// 4 pairs (8 edges) in flight. Output: packed bf16 mean, 32 uints/node.
__global__ __launch_bounds__(256, 6) void gather_mean_kernel(
    const uint32* __restrict__ hb32,   // bf16 rows, 32 uints per node
    const int* __restrict__ rowBeg, const int* __restrict__ deg,
    const int* __restrict__ ss,
    uint32* __restrict__ meanb32,
    int n)
{
    int lane = threadIdx.x & 63;
    int wid = threadIdx.x >> 6;
    int q = lane & 31;
    bool hiHalf = (lane >= 32);

    for (int node = blockIdx.x * 4 + wid; node < n; node += gridDim.x * 4) {
        int dg = deg[node];
        int beg = rowBeg[node];
        float accLo = 0.0f, accHi = 0.0f;
        for (int c = 0; c < dg; c += 64) {
            int cl = min(64, dg - c);
            int idx = (lane < cl) ? ss[beg + c + lane] : 0;
            int np = cl >> 1;
            int p = 0;
            for (; p + 4 <= np; p += 4) {
                int e0 = 2 * p;
                int s0 = hiHalf ? bcasti(idx, e0 + 1) : bcasti(idx, e0 + 0);
                int s1 = hiHalf ? bcasti(idx, e0 + 3) : bcasti(idx, e0 + 2);
                int s2 = hiHalf ? bcasti(idx, e0 + 5) : bcasti(idx, e0 + 4);
                int s3 = hiHalf ? bcasti(idx, e0 + 7) : bcasti(idx, e0 + 6);
                uint32 u0 = hb32[(size_t)s0 * 32 + q];
                uint32 u1 = hb32[(size_t)s1 * 32 + q];
                uint32 u2 = hb32[(size_t)s2 * 32 + q];
                uint32 u3 = hb32[(size_t)s3 * 32 + q];
                accLo += bfLo(u0) + bfLo(u1);
                accHi += bfHi(u0) + bfHi(u1);
                accLo += bfLo(u2) + bfLo(u3);
                accHi += bfHi(u2) + bfHi(u3);
            }
            for (; p < np; ++p) {
                int s = hiHalf ? bcasti(idx, 2 * p + 1) : bcasti(idx, 2 * p);
                uint32 u = hb32[(size_t)s * 32 + q];
                accLo += bfLo(u);
                accHi += bfHi(u);
            }
            if (cl & 1) {                        // odd tail: lo-half only
                int s = bcasti(idx, cl - 1);
                uint32 u = hb32[(size_t)s * 32 + q];
                if (!hiHalf) { accLo += bfLo(u); accHi += bfHi(u); }
            }
        }
        accLo += __shfl_xor(accLo, 32);
        accHi += __shfl_xor(accHi, 32);
        if (!hiHalf) {
            float inv = (dg > 0) ? 1.0f / (float)dg : 0.0f;
            uint32 lo = f2bf(accLo * inv);
            uint32 hi = f2bf(accHi * inv);
            meanb32[(size_t)node * 32 + q] = lo | (hi << 16);
        }
    }
}

// ---------- GEMV layer kernel (R8-proven body, gather removed) ----------
// hout = relu(mean @ Wl + bl + root @ Wr); WITH_MLP adds the fused MLP head.
// mean read as packed bf16 pairs: feature k -> lane k>>1, component k&1.
template <int WITH_MLP>
__global__ __launch_bounds__(256) void gemv_layer_kernel(
    const unsigned short* __restrict__ rootb,   // bf16 root features
    const uint32* __restrict__ meanb32,         // packed bf16 mean
    const float* __restrict__ Wl, const float* __restrict__ bl,
    const float* __restrict__ Wr,
    const float* __restrict__ Wf1, const float* __restrict__ bf1,
    const float* __restrict__ Wf2, const float* __restrict__ bf2,
    unsigned short* __restrict__ houtb,   // bf16 layer output (WITH_MLP=0)
    float* __restrict__ outp,             // final output (WITH_MLP=1)
    int n)
{
    __shared__ float sWlT[D * PAD];
    __shared__ float sWrT[D * PAD];
    __shared__ float sF1T[WITH_MLP ? (DM * PAD) : 1];
    for (int i = threadIdx.x; i < D * D; i += 256) {
        int k = i >> 6, j = i & 63;                      // W[k][j]
        sWlT[j * PAD + k] = Wl[i];
        sWrT[j * PAD + k] = Wr[i];
    }
    if (WITH_MLP) {
        for (int i = threadIdx.x; i < D * DM; i += 256) {
            int k = i >> 5, j = i & 31;                  // Wf1[k][j]
            sF1T[j * PAD + k] = Wf1[i];
        }
    }
    __syncthreads();

    int lane = threadIdx.x & 63;
    int wid = threadIdx.x >> 6;
    const float* rowWl = &sWlT[lane * PAD];
    const float* rowWr = &sWrT[lane * PAD];
    const float* rowF1 = &sF1T[(lane & 31) * PAD];

    float biasMain = bl[lane];
    float f1bias = 0.f, f2w = 0.f, bias2 = 0.f;
    if (WITH_MLP) {
        f1bias = bf1[lane & 31];
        f2w    = Wf2[lane & 31];
        bias2  = bf2[0];
    }

    for (int node = blockIdx.x * 4 + wid; node < n; node += gridDim.x * 4) {
        uint32 mu = meanb32[(size_t)node * 32 + (lane & 31)];
        float mlo = bfLo(mu);                 // feature 2*(lane&31)
        float mhi = bfHi(mu);                 // feature 2*(lane&31)+1
        float x = bf2f(rootb[(size_t)node * D + lane]);

        float acc = biasMain;
#pragma unroll
        for (int k0 = 0; k0 < D; k0 += 4) {
            const int hq = k0 >> 1;           // lane holding features k0,k0+1
            float4 wl = *(const float4*)&rowWl[k0];
            float4 wr = *(const float4*)&rowWr[k0];
            acc += bcastf(mlo, hq + 0) * wl.x + bcastf(x, k0 + 0) * wr.x
                 + bcastf(mhi, hq + 0) * wl.y + bcastf(x, k0 + 1) * wr.y
                 + bcastf(mlo, hq + 1) * wl.z + bcastf(x, k0 + 2) * wr.z
                 + bcastf(mhi, hq + 1) * wl.w + bcastf(x, k0 + 3) * wr.w;
        }

        if (!WITH_MLP) {
            houtb[(size_t)node * D + lane] = f2bf(fmaxf(acc, 0.0f));
        } else {
            float h2 = fmaxf(acc, 0.0f);
            float acc2 = (lane < DM) ? f1bias : 0.0f;
#pragma unroll
            for (int k0 = 0; k0 < D; k0 += 4) {
                float4 f1 = *(const float4*)&rowF1[k0];
                float a0 = bcastf(h2, k0 + 0);
                float a1 = bcastf(h2, k0 + 1);
                float a2 = bcastf(h2, k0 + 2);
                float a3 = bcastf(h2, k0 + 3);
                if (lane < DM)
                    acc2 += a0 * f1.x + a1 * f1.y + a2 * f1.z + a3 * f1.w;
            }
            float pv = (lane < DM) ? fmaxf(acc2, 0.0f) * f2w : 0.0f;
#pragma unroll
            for (int off = 32; off >= 1; off >>= 1) pv += __shfl_xor(pv, off);
            if (lane == 0)
                outp[node] = 1.0f / (1.0f + expf(-(pv + bias2)));
        }
    }
}

extern "C" void kernel_launch(void* const* d_in, const int* in_sizes, int n_in,
                              void* d_out, int out_size, void* d_ws, size_t ws_size,
                              hipStream_t stream)
{
    const float* x   = (const float*)d_in[0];
    const int*   ei  = (const int*)d_in[1];
    const float* W1l = (const float*)d_in[2];
    const float* b1l = (const float*)d_in[3];
    const float* W1r = (const float*)d_in[4];
    const float* W2l = (const float*)d_in[5];
    const float* b2l = (const float*)d_in[6];
    const float* W2r = (const float*)d_in[7];
    const float* Wf1 = (const float*)d_in[8];
    const float* bf1 = (const float*)d_in[9];
    const float* Wf2 = (const float*)d_in[10];
    const float* bf2 = (const float*)d_in[11];
    float* out = (float*)d_out;

    const int* src = ei;            // edge_index[0]
    const int* dst = ei + NE;       // edge_index[1]

    char* ws = (char*)d_ws;
    size_t off = 0;
    auto alloc = [&](size_t bytes) {
        char* p = ws + off;
        off = (off + bytes + 255) & ~(size_t)255;
        return p;
    };
    int* hist      = (int*)alloc((size_t)NN * sizeof(int));
    int* rowBeg    = (int*)alloc((size_t)NN * sizeof(int));
    int* cursor    = (int*)alloc((size_t)NN * sizeof(int));
    int* partials  = (int*)alloc(128 * sizeof(int));
    int* pscan     = (int*)alloc(128 * sizeof(int));
    int* sortedSrc = (int*)alloc((size_t)NE * sizeof(int));
    unsigned short* xb    = (unsigned short*)alloc((size_t)NN * D * sizeof(unsigned short));
    unsigned short* h1b   = (unsigned short*)alloc((size_t)NN * D * sizeof(unsigned short));
    uint32*         meanb = (uint32*)alloc((size_t)NN * (D / 2) * sizeof(uint32));

    dim3 blk(256);

    // ---- x -> bf16 ----
    cvt_bf16_kernel<<<1024, blk, 0, stream>>>(
        (const float4*)x, (ushort4*)xb, NN * D / 4);

    // ---- CSR build (shared by both layers) ----
    hipMemsetAsync(hist, 0, (size_t)NN * sizeof(int), stream);
    hist_kernel<<<2048, blk, 0, stream>>>(dst, hist, NE);
    block_sum_kernel<<<NBLK_SCAN, blk, 0, stream>>>(hist, partials, NN);
    scan_partials_kernel<<<1, 128, 0, stream>>>(partials, pscan, NBLK_SCAN);
    scan_chunk_kernel<<<NBLK_SCAN, blk, 0, stream>>>(hist, pscan, rowBeg, cursor, NN);
    fill_kernel<<<2048, blk, 0, stream>>>(src, dst, cursor, sortedSrc, NE);

    // ---- layer 1: gather mean(xb) -> gemv -> h1b ----
    gather_mean_kernel<<<1536, blk, 0, stream>>>(
        (const uint32*)xb, rowBeg, hist, sortedSrc, meanb, NN);
    gemv_layer_kernel<0><<<1024, blk, 0, stream>>>(
        xb, meanb, W1l, b1l, W1r, Wf1, bf1, Wf2, bf2, h1b, nullptr, NN);

    // ---- layer 2: gather mean(h1b) -> gemv + fused MLP -> out ----
    gather_mean_kernel<<<1536, blk, 0, stream>>>(
        (const uint32*)h1b, rowBeg, hist, sortedSrc, meanb, NN);
    gemv_layer_kernel<1><<<1024, blk, 0, stream>>>(
        h1b, meanb, W2l, b2l, W2r, Wf1, bf1, Wf2, bf2, nullptr, out, NN);
}